// Round 10
// baseline (164.354 us; speedup 1.0000x reference)
//
#include <hip/hip_runtime.h>
#include <type_traits>

// DCNv2 forward, MI355X (gfx950).
//  k_pre:     x NCHW f32 -> xbf NHWC bf16 (direct strided loads, perm-pack,
//             b128 stores, no LDS) + coalesced weight repack.
//  k_offconv: implicit-im2col MFMA GEMM -> om[r][32] f32 (bias+sigmoid).
//  k_gemm_fused v4: grid (256,1), BM=64 x BN=256 — every output row sampled
//             ONCE chip-wide (v3's (128,2) grid blended each row twice).
//             B-operand bypasses LDS entirely: per-wave register prefetch of
//             MFMA B-frags straight from L2-resident wmain (static addresses).
//             LDS holds only the 8 KB A-tile, double-buffered, ONE lgkm-only
//             barrier per kstep. Waves 0-7 sample (8ch/thread, depth-2 gather
//             prefetch); waves 8-15 only B-prefetch + MFMA. All prefetch slots
//             are integral_constants (R7/R8 scratch-spill lesson).

typedef __bf16 bf16x8 __attribute__((ext_vector_type(8)));
typedef float  f32x4  __attribute__((ext_vector_type(4)));
typedef unsigned short ushort8 __attribute__((ext_vector_type(8)));
typedef unsigned int   uint4v  __attribute__((ext_vector_type(4)));

#define XBF_OFF   0u            // 4*4096*256*2  = 8,388,608
#define WREP_OFF  8388608u      // 32*2304*2     =   147,456
#define WMAIN_OFF 8536064u      // 256*2304*2    = 1,179,648
#define OM_OFF    9715712u      // 16384*32*4    = 2,097,152

#define LGKM0_BAR() do { __builtin_amdgcn_s_waitcnt(0xC07F); __builtin_amdgcn_s_barrier(); } while (0)

template <int N> using ic = std::integral_constant<int, N>;

__device__ __forceinline__ unsigned short f2bf(float f) {
  unsigned int u = __float_as_uint(f);
  u += 0x7fffu + ((u >> 16) & 1u);
  return (unsigned short)(u >> 16);
}
__device__ __forceinline__ float bf2f(unsigned short h) {
  return __uint_as_float(((unsigned int)h) << 16);
}

// ---------------- transpose (no LDS) + coalesced repack ----------------
// transpose role: block b: n = b>>9, cq = (b>>4)&31 (8-channel octet), yb = b&15.
// thread t: yx = yb*256 + t. 8 strided f32 loads (each coalesced across yx),
// perm-pack to 4 dwords, one b128 store (full cache lines).
__global__ __launch_bounds__(256) void k_pre(const float* __restrict__ x,
                                             const float* __restrict__ w_off,
                                             const float* __restrict__ dcn_w,
                                             unsigned short* __restrict__ xbf,
                                             unsigned short* __restrict__ wrep,
                                             unsigned short* __restrict__ wmain) {
  __shared__ unsigned short lsh[2304];
  int b = blockIdx.x;
  int t = threadIdx.x;
  if (b < 2048) {
    int n  = b >> 9;
    int cq = (b >> 4) & 31;
    int yx = (b & 15) * 256 + t;
    const float* xp = x + ((size_t)(n * 256 + cq * 8) << 12) + yx;
    float v[8];
#pragma unroll
    for (int j = 0; j < 8; ++j) v[j] = xp[(size_t)j << 12];
    uint4v rs;
#pragma unroll
    for (int p = 0; p < 4; ++p) {
      unsigned ua = __float_as_uint(v[2 * p])     + 0x8000u;
      unsigned ub = __float_as_uint(v[2 * p + 1]) + 0x8000u;
      rs[p] = __builtin_amdgcn_perm(ub, ua, 0x07060302u);
    }
    *(uint4v*)(xbf + ((size_t)((n << 12) + yx)) * 256 + cq * 8) = rs;
  } else {                      // repack role: one block per output channel
    int ocb = b - 2048;
    const float* src;
    unsigned short* dst;
    int oc;
    if (ocb < 32) { oc = ocb; src = w_off; dst = wrep; }
    else          { oc = ocb - 32; src = dcn_w; dst = wmain; }
    if (ocb < 32 && oc >= 27) {
#pragma unroll
      for (int j = 0; j < 9; ++j) dst[oc * 2304 + j * 256 + t] = 0;
      return;
    }
    const float* base = src + (size_t)oc * 2304;
#pragma unroll
    for (int j = 0; j < 9; ++j) lsh[j * 256 + t] = f2bf(base[t * 9 + j]);
    __syncthreads();
#pragma unroll
    for (int j = 0; j < 9; ++j) dst[oc * 2304 + j * 256 + t] = lsh[j * 256 + t];
  }
}

// ---------------- offset-field conv: K-split-4, BK=64, depth-2 prefetch ------
__global__ __launch_bounds__(1024) void k_offconv(const unsigned short* __restrict__ xbf,
                                                  const unsigned short* __restrict__ wrep,
                                                  const float* __restrict__ bias,
                                                  float* __restrict__ om) {
  __shared__ __align__(16) unsigned short SHa[4][64 * 64];
  __shared__ __align__(16) unsigned short SHb[4][32 * 64];
  int t = threadIdx.x;
  int wave = t >> 6, lane = t & 63;
  int grp = wave >> 2, wv = wave & 3;
  int tg = t & 255;
  int bm = ((blockIdx.x & 7) << 5) + (blockIdx.x >> 3);   // XCD swizzle
  int n = bm >> 6, oy = bm & 63;

  unsigned short* As = SHa[grp];
  unsigned short* Bs = SHb[grp];

  int arow = tg >> 2, acc4 = tg & 3;
  int brow = tg >> 3, bch = tg & 7;

  f32x4 acc0 = {0.f, 0.f, 0.f, 0.f};
  f32x4 acc1 = {0.f, 0.f, 0.f, 0.f};

  ushort8 av[2][2]; ushort8 bv[2];
  auto prefetch = [&](int ktg, auto slotc) {
    constexpr int slot = decltype(slotc)::value;
    int kk = ktg >> 2;
    int c0 = (ktg & 3) * 64;
    int dy = kk / 3 - 1, dx = kk % 3 - 1;
    int yy = oy + dy, xxg = arow + dx;
    bool ok = ((unsigned)yy < 64u) && ((unsigned)xxg < 64u);
    const unsigned short* p = xbf + (size_t)(((n * 64 + yy) * 64 + xxg) * 256 + c0 + acc4 * 16);
#pragma unroll
    for (int g = 0; g < 2; ++g)
      av[slot][g] = ok ? *(const ushort8*)(p + g * 8) : (ushort8){0,0,0,0,0,0,0,0};
    bv[slot] = *(const ushort8*)(wrep + (size_t)brow * 2304 + ktg * 64 + bch * 8);
  };

  int k0 = grp * 9;
  prefetch(k0, ic<0>{});
  prefetch(k0 + 1, ic<1>{});
  int mr = lane & 15, q = lane >> 4;

  auto step = [&](int kt, auto slotc) {
    constexpr int slot = decltype(slotc)::value;
    LGKM0_BAR();
#pragma unroll
    for (int g = 0; g < 2; ++g) {
      int ch = (acc4 * 2 + g) ^ (arow & 7);
      *(ushort8*)&As[arow * 64 + ch * 8] = av[slot][g];
    }
    { int ch = bch ^ (brow & 7);
      *(ushort8*)&Bs[brow * 64 + ch * 8] = bv[slot]; }
    if (kt + 2 < 9) prefetch(k0 + kt + 2, slotc);
    LGKM0_BAR();
#pragma unroll
    for (int kh = 0; kh < 2; ++kh) {
      int coff = ((q + kh * 4) ^ (mr & 7)) * 8;
      bf16x8 a  = *(const bf16x8*)&As[(wv * 16 + mr) * 64 + coff];
      bf16x8 b0 = *(const bf16x8*)&Bs[mr * 64 + coff];
      bf16x8 b1 = *(const bf16x8*)&Bs[(16 + mr) * 64 + coff];
      acc0 = __builtin_amdgcn_mfma_f32_16x16x32_bf16(a, b0, acc0, 0, 0, 0);
      acc1 = __builtin_amdgcn_mfma_f32_16x16x32_bf16(a, b1, acc1, 0, 0, 0);
    }
  };
  for (int kp = 0; kp < 4; ++kp) {
    step(2 * kp, ic<0>{});
    step(2 * kp + 1, ic<1>{});
  }
  step(8, ic<0>{});

  float* scratch = (float*)&SHa[0][0];
  __syncthreads();
  if (grp > 0) {
#pragma unroll
    for (int nt = 0; nt < 2; ++nt) {
      f32x4 a = nt ? acc1 : acc0;
#pragma unroll
      for (int rg = 0; rg < 4; ++rg)
        scratch[(grp - 1) * 2048 + (wv * 16 + q * 4 + rg) * 32 + nt * 16 + mr] = a[rg];
    }
  }
  __syncthreads();
  if (grp == 0) {
    int r0 = bm * 64;
#pragma unroll
    for (int nt = 0; nt < 2; ++nt) {
      f32x4 a = nt ? acc1 : acc0;
      int oc = nt * 16 + mr;
      float bvl = (oc < 27) ? bias[oc] : 0.f;
#pragma unroll
      for (int rg = 0; rg < 4; ++rg) {
        int pl = wv * 16 + q * 4 + rg;
        float v = a[rg] + bvl + scratch[pl * 32 + oc] +
                  scratch[2048 + pl * 32 + oc] + scratch[4096 + pl * 32 + oc];
        if (oc >= 18 && oc < 27) v = 1.f / (1.f + __expf(-v));
        om[(r0 + pl) * 32 + oc] = v;
      }
    }
  }
}

// ---------------- fused deformable-im2col GEMM v4 ----------------------------
__global__ __launch_bounds__(1024) void k_gemm_fused(const unsigned short* __restrict__ xbf,
                                                     const float* __restrict__ om,
                                                     const unsigned short* __restrict__ wB,
                                                     float* __restrict__ out) {
  __shared__ __align__(16) unsigned short Ab[2][64 * 64];   // 16 KB total
  int t = threadIdx.x;
  int wave = t >> 6, lane = t & 63;
  int wm = wave & 1, wn = wave >> 1;        // 2 (M) x 8 (N) wave grid, 32x32 tiles
  int bmx = ((blockIdx.x & 7) << 5) + (blockIdx.x >> 3);    // XCD swizzle
  int r0 = bmx * 64;

  int mr = lane & 15, q = lane >> 4;
  bool sampler = (t < 512);
  int srow = t >> 3;            // 0..63 (samplers)
  int sch  = (t & 7) * 8;
  int r = r0 + (sampler ? srow : 0);
  int n = r >> 12, yx = r & 4095, oy = yx >> 6, ox = yx & 63;
  const unsigned short* xb = xbf + (size_t)n * (4096 * 256);
  const float* omr = om + (size_t)r * 32;
  int wch = ((t & 7) ^ (srow & 7)) * 8;     // swizzled A-write offset

  // per-lane B pointers (static addresses; oc row = wn*32 + nt*16 + mr, kchunk q)
  const unsigned short* Bl0 = wB + (size_t)(wn * 32 + mr) * 2304 + q * 8;
  const unsigned short* Bl1 = Bl0 + (size_t)16 * 2304;

  f32x4 acc[2][2];
#pragma unroll
  for (int mt = 0; mt < 2; ++mt)
#pragma unroll
    for (int nt = 0; nt < 2; ++nt) acc[mt][nt] = (f32x4){0.f, 0.f, 0.f, 0.f};

  float pv_y, pv_x, pv_m;
  float cw1, cw2, cw3, cw4;
  int a1, a2, a3, a4;
  float wbuf[2][4];

  auto loadom = [&](int kk) {
    pv_y = omr[2 * kk]; pv_x = omr[2 * kk + 1]; pv_m = omr[18 + kk];
  };
  auto params = [&](int kk) {
    float py = (float)(oy + kk / 3) + pv_y;
    float px = (float)(ox + kk % 3) + pv_x;
    float m = pv_m;
    py = fminf(fmaxf(py, 0.f), 65.f);
    px = fminf(fmaxf(px, 0.f), 65.f);
    float fy = floorf(py), fx = floorf(px);
    float ly = py - fy, lx = px - fx;
    float hy = 1.f - ly, hx = 1.f - lx;
    int iy = (int)fy, ix = (int)fx;
    bool yv0 = (iy >= 1) && (iy <= 64);
    bool yv1 = (iy <= 63);
    bool xv0 = (ix >= 1) && (ix <= 64);
    bool xv1 = (ix <= 63);
    int y0 = min(max(iy - 1, 0), 63);
    int y1 = min(iy, 63);
    int x0 = min(max(ix - 1, 0), 63);
    int x1 = min(ix, 63);
    cw1 = (yv0 && xv0) ? hy * hx * m : 0.f;
    cw2 = (yv0 && xv1) ? hy * lx * m : 0.f;
    cw3 = (yv1 && xv0) ? ly * hx * m : 0.f;
    cw4 = (yv1 && xv1) ? ly * lx * m : 0.f;
    a1 = ((y0 << 6) + x0) * 256;
    a2 = ((y0 << 6) + x1) * 256;
    a3 = ((y1 << 6) + x0) * 256;
    a4 = ((y1 << 6) + x1) * 256;
  };

  ushort8 g1[2], g2[2], g3[2], g4[2];
  bf16x8 bfr[2][2][2];                       // [slot][nt][kh]
  auto issueA = [&](int k, auto slotc) {
    constexpr int slot = decltype(slotc)::value;
    wbuf[slot][0] = cw1; wbuf[slot][1] = cw2; wbuf[slot][2] = cw3; wbuf[slot][3] = cw4;
    int c = (k & 3) * 64 + sch;
    g1[slot] = *(const ushort8*)(xb + a1 + c);
    g2[slot] = *(const ushort8*)(xb + a2 + c);
    g3[slot] = *(const ushort8*)(xb + a3 + c);
    g4[slot] = *(const ushort8*)(xb + a4 + c);
  };
  auto issueB = [&](int k, auto slotc) {
    constexpr int slot = decltype(slotc)::value;
#pragma unroll
    for (int kh = 0; kh < 2; ++kh) {
      bfr[slot][0][kh] = *(const bf16x8*)(Bl0 + k * 64 + kh * 32);
      bfr[slot][1][kh] = *(const bf16x8*)(Bl1 + k * 64 + kh * 32);
    }
  };

  if (sampler) {
    loadom(0);
    params(0);
    loadom(1);
    issueA(0, ic<0>{});
    issueA(1, ic<1>{});
  }
  issueB(0, ic<0>{});

  auto step = [&](int k, auto slotc) {
    constexpr int slot = decltype(slotc)::value;
    if (sampler) {
      // blend + perm-pack (gathers issued at k-2)
      uint4v rs;
#pragma unroll
      for (int p = 0; p < 4; ++p) {
        float va = wbuf[slot][0] * bf2f(g1[slot][2 * p])     + wbuf[slot][1] * bf2f(g2[slot][2 * p]) +
                   wbuf[slot][2] * bf2f(g3[slot][2 * p])     + wbuf[slot][3] * bf2f(g4[slot][2 * p]);
        float vb = wbuf[slot][0] * bf2f(g1[slot][2 * p + 1]) + wbuf[slot][1] * bf2f(g2[slot][2 * p + 1]) +
                   wbuf[slot][2] * bf2f(g3[slot][2 * p + 1]) + wbuf[slot][3] * bf2f(g4[slot][2 * p + 1]);
        unsigned ua = __float_as_uint(va) + 0x8000u;
        unsigned ub = __float_as_uint(vb) + 0x8000u;
        rs[p] = __builtin_amdgcn_perm(ub, ua, 0x07060302u);
      }
      *(uint4v*)&Ab[slot][srow * 64 + wch] = rs;    // buf parity == slot parity
      if (k + 2 < 36) {
        if (((k + 2) & 3) == 0) {
          int kk = (k + 2) >> 2;
          params(kk);
          loadom(kk < 8 ? kk + 1 : 8);
        }
        issueA(k + 2, slotc);
      }
    }
    if (k + 1 < 36) issueB(k + 1, ic<slot ^ 1>{});
    LGKM0_BAR();                 // A-writes visible; gathers/B stay in flight
#pragma unroll
    for (int kh = 0; kh < 2; ++kh) {
      int coff = ((q + kh * 4) ^ (mr & 7)) * 8;
      bf16x8 af[2];
#pragma unroll
      for (int mt = 0; mt < 2; ++mt)
        af[mt] = *(const bf16x8*)&Ab[slot][(wm * 32 + mt * 16 + mr) * 64 + coff];
#pragma unroll
      for (int mt = 0; mt < 2; ++mt)
#pragma unroll
        for (int nt = 0; nt < 2; ++nt)
          acc[mt][nt] = __builtin_amdgcn_mfma_f32_16x16x32_bf16(af[mt], bfr[slot][nt][kh], acc[mt][nt], 0, 0, 0);
    }
  };

  for (int kp = 0; kp < 18; ++kp) {
    step(2 * kp, ic<0>{});
    step(2 * kp + 1, ic<1>{});
  }

  // epilogue: direct stores
#pragma unroll
  for (int mt = 0; mt < 2; ++mt)
#pragma unroll
    for (int nt = 0; nt < 2; ++nt) {
      int p = r0 + wm * 32 + mt * 16 + q * 4;
      int o = wn * 32 + nt * 16 + mr;
      int nn = p >> 12, pyx = p & 4095;
      *(f32x4*)(out + ((size_t)(nn * 256 + o) << 12) + pyx) = acc[mt][nt];
    }
}

extern "C" void kernel_launch(void* const* d_in, const int* in_sizes, int n_in,
                              void* d_out, int out_size, void* d_ws, size_t ws_size,
                              hipStream_t stream) {
  const float* x     = (const float*)d_in[0];
  const float* w_off = (const float*)d_in[1];
  const float* b_off = (const float*)d_in[2];
  const float* dcn_w = (const float*)d_in[3];
  float* out = (float*)d_out;
  char* ws = (char*)d_ws;
  unsigned short* xbf   = (unsigned short*)(ws + XBF_OFF);
  unsigned short* wrep  = (unsigned short*)(ws + WREP_OFF);
  unsigned short* wmain = (unsigned short*)(ws + WMAIN_OFF);
  float*          om    = (float*)(ws + OM_OFF);

  k_pre<<<2048 + 288, 256, 0, stream>>>(x, w_off, dcn_w, xbf, wrep, wmain);
  k_offconv<<<256, 1024, 0, stream>>>(xbf, wrep, b_off, om);
  k_gemm_fused<<<256, 1024, 0, stream>>>(xbf, om, wmain, out);
}